// Round 1
// baseline (46.170 us; speedup 1.0000x reference)
//
#include <hip/hip_runtime.h>

// out[b] = dot(x[b,:], W[actions[b],:]) + bias[actions[b]]        (is_global==0)
// out[b] = max_p ( dot(x[b,:], W[p,:]) + bias[p] )                (is_global!=0)
//
// B=65536, C=1024, P=4, fp32. Memory-bound: 256 MiB x-read dominates.

#define BLOCK 256
#define WAVES_PER_BLOCK (BLOCK / 64)
#define MAX_P 8
#define MAX_WLDS 4096   // P*C floats staged in LDS (P=4, C=1024 -> 16 KiB)

__global__ __launch_bounds__(BLOCK, 4) void ranker_kernel(
    const float* __restrict__ x,        // [B, C]
    const float* __restrict__ W,        // [P, C]
    const float* __restrict__ bias,     // [P]
    const int*   __restrict__ actions,  // [B]
    const int*   __restrict__ is_global_p,
    float* __restrict__ out,            // [B]
    int B, int C, int P)
{
    __shared__ float Wlds[MAX_WLDS];
    __shared__ float blds[MAX_P];

    const int tid = threadIdx.x;

    // Stage W into LDS (vectorized, cooperative). P*C is a multiple of 4.
    const int nvec = (P * C) >> 2;
    const float4* Wv = reinterpret_cast<const float4*>(W);
    float4* Wldsv = reinterpret_cast<float4*>(Wlds);
    for (int i = tid; i < nvec; i += BLOCK) Wldsv[i] = Wv[i];
    if (tid < P) blds[tid] = bias[tid];
    __syncthreads();

    const int lane  = tid & 63;
    const int wid   = tid >> 6;
    const int gwave = blockIdx.x * WAVES_PER_BLOCK + wid;
    const int nwav  = gridDim.x * WAVES_PER_BLOCK;
    const int ig    = *is_global_p;     // wave-uniform scalar
    const int cvec  = C >> 2;           // float4s per row (256 for C=1024)

    if (!ig) {
        for (int row = gwave; row < B; row += nwav) {
            const float4* xr = reinterpret_cast<const float4*>(x) + (size_t)row * cvec;
            const int a = actions[row];
            const float4* wr = reinterpret_cast<const float4*>(Wlds + a * C);
            float s = 0.f;
            #pragma unroll 4
            for (int j = lane; j < cvec; j += 64) {
                float4 xv = xr[j];
                float4 wv = wr[j];
                s += xv.x * wv.x + xv.y * wv.y + xv.z * wv.z + xv.w * wv.w;
            }
            #pragma unroll
            for (int off = 32; off > 0; off >>= 1)
                s += __shfl_down(s, off, 64);
            if (lane == 0) out[row] = s + blds[a];
        }
    } else {
        for (int row = gwave; row < B; row += nwav) {
            const float4* xr = reinterpret_cast<const float4*>(x) + (size_t)row * cvec;
            float s0 = 0.f, s1 = 0.f, s2 = 0.f, s3 = 0.f;
            #pragma unroll 4
            for (int j = lane; j < cvec; j += 64) {
                float4 xv = xr[j];
                float4 w0 = reinterpret_cast<const float4*>(Wlds + 0 * C)[j];
                float4 w1 = reinterpret_cast<const float4*>(Wlds + 1 * C)[j];
                float4 w2 = reinterpret_cast<const float4*>(Wlds + 2 * C)[j];
                float4 w3 = reinterpret_cast<const float4*>(Wlds + 3 * C)[j];
                s0 += xv.x * w0.x + xv.y * w0.y + xv.z * w0.z + xv.w * w0.w;
                s1 += xv.x * w1.x + xv.y * w1.y + xv.z * w1.z + xv.w * w1.w;
                s2 += xv.x * w2.x + xv.y * w2.y + xv.z * w2.z + xv.w * w2.w;
                s3 += xv.x * w3.x + xv.y * w3.y + xv.z * w3.z + xv.w * w3.w;
            }
            #pragma unroll
            for (int off = 32; off > 0; off >>= 1) {
                s0 += __shfl_down(s0, off, 64);
                s1 += __shfl_down(s1, off, 64);
                s2 += __shfl_down(s2, off, 64);
                s3 += __shfl_down(s3, off, 64);
            }
            if (lane == 0) {
                float m = s0 + blds[0];
                m = fmaxf(m, s1 + blds[1]);
                m = fmaxf(m, s2 + blds[2]);
                m = fmaxf(m, s3 + blds[3]);
                out[row] = m;
            }
        }
    }
}

extern "C" void kernel_launch(void* const* d_in, const int* in_sizes, int n_in,
                              void* d_out, int out_size, void* d_ws, size_t ws_size,
                              hipStream_t stream) {
    const float* x        = (const float*)d_in[0];
    const float* W        = (const float*)d_in[1];
    const float* bias     = (const float*)d_in[2];
    const int*   actions  = (const int*)d_in[3];
    const int*   is_glob  = (const int*)d_in[4];
    float* out            = (float*)d_out;

    const int B = in_sizes[3];            // actions count
    const int P = in_sizes[2];            // bias count
    const int C = in_sizes[0] / B;        // 1024

    // Memory-bound: cap grid at ~2048 blocks, grid-stride the rows.
    int total_waves_needed = B;                       // 1 wave per row
    int blocks = (total_waves_needed + WAVES_PER_BLOCK - 1) / WAVES_PER_BLOCK;
    if (blocks > 2048) blocks = 2048;

    ranker_kernel<<<blocks, BLOCK, 0, stream>>>(x, W, bias, actions, is_glob,
                                                out, B, C, P);
}